// Round 7
// baseline (1063.015 us; speedup 1.0000x reference)
//
#include <hip/hip_runtime.h>
#include <hip/hip_bf16.h>

// Problem constants (fixed by reference)
constexpr int GN = 100000;   // nodes
constexpr int GE = 1600000;  // edges
constexpr float FN = 100000.0f;
constexpr float BN_EPS = 1e-5f;

typedef __attribute__((ext_vector_type(8))) short bf16x8;
typedef __attribute__((ext_vector_type(4))) float f32x4;
typedef __bf16 bfp2 __attribute__((ext_vector_type(2)));

#if __has_builtin(__builtin_amdgcn_fdot2_f32_bf16)
#define HAVE_DOT2 1
#else
#define HAVE_DOT2 0
#endif

__device__ __forceinline__ unsigned packbf2(float a, float b) {
    __hip_bfloat162 h = __float22bfloat162_rn(float2{a, b});
    union { __hip_bfloat162 h2; unsigned u; } cv;
    cv.h2 = h;
    return cv.u;
}

__device__ __forceinline__ unsigned short bf16rn(float f) {
    unsigned u = __builtin_bit_cast(unsigned, f);
    unsigned r = (u + 0x7FFF + ((u >> 16) & 1)) >> 16;
    return (unsigned short)r;
}

__device__ __forceinline__ float bflo(unsigned u) {
    return __builtin_bit_cast(float, u << 16);
}
__device__ __forceinline__ float bfhi(unsigned u) {
    return __builtin_bit_cast(float, u & 0xFFFF0000u);
}
__device__ __forceinline__ float bfu16(unsigned short u) {
    return __builtin_bit_cast(float, (unsigned)u << 16);
}

// ---------------- CSR build ----------------

__global__ __launch_bounds__(256) void hist_kernel(const int* __restrict__ dst,
                                                   int* __restrict__ deg) {
    for (int i = blockIdx.x * blockDim.x + threadIdx.x; i < GE; i += gridDim.x * blockDim.x)
        atomicAdd(&deg[dst[i]], 1);
}

// block sums for scan + folded weight conversion (saves a dispatch)
__global__ __launch_bounds__(256) void bsum_kernel(const int* __restrict__ deg,
                                                   int* __restrict__ bsum,
                                                   const float* __restrict__ l1w,
                                                   const float* __restrict__ l2w,
                                                   const float* __restrict__ c1w,
                                                   unsigned short* __restrict__ wb) {
    int b = blockIdx.x;
    int i0 = b * 1024 + threadIdx.x * 4;
    int s = 0;
#pragma unroll
    for (int k = 0; k < 4; ++k) {
        int i = i0 + k;
        if (i < GN) s += deg[i];
    }
    for (int o = 32; o >= 1; o >>= 1) s += __shfl_down(s, o, 64);
    __shared__ int ws[4];
    if ((threadIdx.x & 63) == 0) ws[threadIdx.x >> 6] = s;
    __syncthreads();
    if (threadIdx.x == 0) bsum[b] = ws[0] + ws[1] + ws[2] + ws[3];
    for (int i = b * 256 + threadIdx.x; i < 40960; i += gridDim.x * 256) {
        float v;
        if (i < 16384) v = l1w[i];
        else if (i < 32768) v = l2w[i - 16384];
        else v = c1w[i - 32768];
        wb[i] = bf16rn(v);
    }
}

__global__ void bscan_kernel(const int* __restrict__ bsum, int* __restrict__ bbase,
                             int* __restrict__ offEnd, int nb) {
    int t = threadIdx.x;  // 64 threads, 1 wave
    int carry = 0;
    for (int base = 0; base < nb; base += 64) {
        int v = (base + t < nb) ? bsum[base + t] : 0;
        int incl = v;
        for (int o = 1; o < 64; o <<= 1) {
            int u = __shfl_up(incl, o, 64);
            if (t >= o) incl += u;
        }
        if (base + t < nb) bbase[base + t] = carry + incl - v;
        carry += __shfl(incl, 63, 64);
    }
    if (t == 0) offEnd[0] = carry;
}

// writes exclusive prefix to BOTH off[] and (in place) cursor[] (== deg array)
__global__ __launch_bounds__(256) void bscatter_kernel(int* __restrict__ deg,
                                                       const int* __restrict__ bbase,
                                                       int* __restrict__ off) {
    int b = blockIdx.x;
    int t = threadIdx.x;
    int i0 = b * 1024 + t * 4;
    int v[4];
    int s = 0;
#pragma unroll
    for (int k = 0; k < 4; ++k) {
        int i = i0 + k;
        v[k] = (i < GN) ? deg[i] : 0;
        s += v[k];
    }
    int incl = s;
    int lane = t & 63;
    for (int o = 1; o < 64; o <<= 1) {
        int u = __shfl_up(incl, o, 64);
        if (lane >= o) incl += u;
    }
    __shared__ int wsum[4];
    if (lane == 63) wsum[t >> 6] = incl;
    __syncthreads();
    int w = t >> 6;
    int wb = 0;
#pragma unroll
    for (int k = 0; k < 4; ++k)
        if (k < w) wb += wsum[k];
    int ex = bbase[b] + wb + incl - s;
#pragma unroll
    for (int k = 0; k < 4; ++k) {
        int i = i0 + k;
        if (i < GN) { off[i] = ex; deg[i] = ex; }
        ex += v[k];
    }
}

// counting-sort: scatter ONLY the 4B permutation (L2 coalesces the writeback);
// also zero the layer-0 stats buffer.
__global__ __launch_bounds__(256) void fill_lite_kernel(const int* __restrict__ dst,
                                                        int* __restrict__ cursor,
                                                        int* __restrict__ eids,
                                                        float* __restrict__ zeroBuf) {
    if (blockIdx.x == 0 && threadIdx.x < 128) zeroBuf[threadIdx.x] = 0.f;
    for (int i = blockIdx.x * blockDim.x + threadIdx.x; i < GE; i += gridDim.x * blockDim.x) {
        int pos = atomicAdd(&cursor[dst[i]], 1);
        eids[pos] = i;
    }
}

// gather-based reorder: coalesced reads of eids, gathers of raw attr (one 64B
// line per edge, L3-warm) and src, fully coalesced writes of sorted arrays.
__global__ __launch_bounds__(256) void reorder_kernel(const int* __restrict__ eids,
                                                      const int* __restrict__ src,
                                                      const float4* __restrict__ attr,
                                                      int* __restrict__ srcS,
                                                      unsigned* __restrict__ attrS) {
    for (int p = blockIdx.x * blockDim.x + threadIdx.x; p < GE; p += gridDim.x * blockDim.x) {
        int eid = eids[p];
        srcS[p] = src[eid];
        const float4* a = attr + (size_t)eid * 4;
        float4 a0 = a[0], a1 = a[1], a2 = a[2], a3 = a[3];
        uint4 ua, ub;
        ua.x = packbf2(a0.x, a0.y); ua.y = packbf2(a0.z, a0.w);
        ua.z = packbf2(a1.x, a1.y); ua.w = packbf2(a1.z, a1.w);
        ub.x = packbf2(a2.x, a2.y); ub.y = packbf2(a2.z, a2.w);
        ub.z = packbf2(a3.x, a3.y); ub.w = packbf2(a3.z, a3.w);
        uint4* out = (uint4*)(attrS + (size_t)p * 8);
        out[0] = ua;
        out[1] = ub;
    }
}

// ---------------- column stats on x (+ bf16 conversion of x) ----------------

__global__ __launch_bounds__(256) void col_stats64(const float* __restrict__ in,
                                                   float* __restrict__ sum,
                                                   float* __restrict__ sq,
                                                   unsigned short* __restrict__ outb) {
    int c = threadIdx.x & 63;
    int lr = threadIdx.x >> 6;
    float s = 0.f, q = 0.f;
    for (int r = blockIdx.x * 4 + lr; r < GN; r += gridDim.x * 4) {
        float v = in[(size_t)r * 64 + c];
        s += v;
        q += v * v;
        outb[(size_t)r * 64 + c] = bf16rn(v);
    }
    __shared__ float S[256];
    S[threadIdx.x] = s;
    __syncthreads();
    if (threadIdx.x < 64) {
        float a = S[threadIdx.x] + S[threadIdx.x + 64] + S[threadIdx.x + 128] + S[threadIdx.x + 192];
        atomicAdd(&sum[threadIdx.x], a);
    }
    __syncthreads();
    S[threadIdx.x] = q;
    __syncthreads();
    if (threadIdx.x < 64) {
        float a = S[threadIdx.x] + S[threadIdx.x + 64] + S[threadIdx.x + 128] + S[threadIdx.x + 192];
        atomicAdd(&sq[threadIdx.x], a);
    }
}

// ---------------- fused BN(pre) + GINE aggregation ----------------
// One wave per node (lane = feature). Uniform s_loads for src ids / attr rows;
// edge-linear via v_dot2_f32_bf16. bf16 gathers and bf16 self-term.

#if HAVE_DOT2
__device__ __forceinline__ float edot(uint4 a, uint4 b, const bfp2* __restrict__ wq,
                                      float e) {
    e = __builtin_amdgcn_fdot2_f32_bf16(__builtin_bit_cast(bfp2, a.x), wq[0], e, false);
    e = __builtin_amdgcn_fdot2_f32_bf16(__builtin_bit_cast(bfp2, a.y), wq[1], e, false);
    e = __builtin_amdgcn_fdot2_f32_bf16(__builtin_bit_cast(bfp2, a.z), wq[2], e, false);
    e = __builtin_amdgcn_fdot2_f32_bf16(__builtin_bit_cast(bfp2, a.w), wq[3], e, false);
    e = __builtin_amdgcn_fdot2_f32_bf16(__builtin_bit_cast(bfp2, b.x), wq[4], e, false);
    e = __builtin_amdgcn_fdot2_f32_bf16(__builtin_bit_cast(bfp2, b.y), wq[5], e, false);
    e = __builtin_amdgcn_fdot2_f32_bf16(__builtin_bit_cast(bfp2, b.z), wq[6], e, false);
    e = __builtin_amdgcn_fdot2_f32_bf16(__builtin_bit_cast(bfp2, b.w), wq[7], e, false);
    return e;
}
#else
__device__ __forceinline__ float edot(uint4 a, uint4 b, const float* __restrict__ w,
                                      float e) {
    e = fmaf(bflo(a.x), w[0], e);  e = fmaf(bfhi(a.x), w[1], e);
    e = fmaf(bflo(a.y), w[2], e);  e = fmaf(bfhi(a.y), w[3], e);
    e = fmaf(bflo(a.z), w[4], e);  e = fmaf(bfhi(a.z), w[5], e);
    e = fmaf(bflo(a.w), w[6], e);  e = fmaf(bfhi(a.w), w[7], e);
    e = fmaf(bflo(b.x), w[8], e);  e = fmaf(bfhi(b.x), w[9], e);
    e = fmaf(bflo(b.y), w[10], e); e = fmaf(bfhi(b.y), w[11], e);
    e = fmaf(bflo(b.z), w[12], e); e = fmaf(bfhi(b.z), w[13], e);
    e = fmaf(bflo(b.w), w[14], e); e = fmaf(bfhi(b.w), w[15], e);
    return e;
}
#endif

__global__ __launch_bounds__(256) void aggregate_kernel(
    const unsigned short* __restrict__ hb,  // bf16 features (gather + self)
    const float* __restrict__ sumv, const float* __restrict__ sqv,
    const float* __restrict__ bnw, const float* __restrict__ bnb,
    int leaky,
    const int* __restrict__ off,
    const int* __restrict__ srcS,
    const unsigned* __restrict__ attrS,     // bf16-packed rows, 8 uints each
    const float* __restrict__ Wle, const float* __restrict__ ble,
    const float* __restrict__ epsArr, int layer,
    unsigned short* __restrict__ zb,        // bf16 output (gemm1 input)
    float* __restrict__ zeroBuf) {
    if (blockIdx.x == 0 && threadIdx.x < 128) zeroBuf[threadIdx.x] = 0.f;
    const int d = threadIdx.x & 63;
    const int node = __builtin_amdgcn_readfirstlane(blockIdx.x * 4 + (threadIdx.x >> 6));

    float mean = sumv[d] / FN;
    float var = sqv[d] / FN - mean * mean;
    float cA = rsqrtf(var + BN_EPS) * bnw[d];
    float cB = bnb[d] - mean * cA;

#if HAVE_DOT2
    bfp2 wq[8];
#pragma unroll
    for (int k = 0; k < 8; ++k) {
        float2 t = *(const float2*)(Wle + d * 16 + k * 2);
        bfp2 v = {(__bf16)t.x, (__bf16)t.y};
        wq[k] = v;
    }
#else
    float wq[16];
#pragma unroll
    for (int k = 0; k < 16; k += 4) {
        float4 t = *(const float4*)(Wle + d * 16 + k);
        wq[k] = t.x; wq[k + 1] = t.y; wq[k + 2] = t.z; wq[k + 3] = t.w;
    }
#endif
    float be = ble[d];
    float epsv = 1.0f + epsArr[layer];

    int p0 = off[node], p1 = off[node + 1];              // uniform -> s_load
    float hv = bfu16(hb[(((unsigned)node) << 6) + d]);   // issue early

    float acc = 0.0f;
    int p = p0;
    int pfull = p0 + ((p1 - p0) & ~7);
    for (; p < pfull; p += 8) {              // full groups: no masking
        int idx[8];
#pragma unroll
        for (int j = 0; j < 8; ++j) idx[j] = srcS[p + j];  // s_load (contiguous)
        float g[8];
#pragma unroll
        for (int j = 0; j < 8; ++j)
            g[j] = bfu16(hb[(((unsigned)idx[j]) << 6) + d]);  // 32-bit offset gathers
#pragma unroll
        for (int j = 0; j < 8; ++j) {
            const uint4* ar = (const uint4*)(attrS + (size_t)(p + j) * 8);
            float e = edot(ar[0], ar[1], wq, be);
            float gg = g[j] * cA + cB;
            if (leaky) gg = fmaxf(gg, 0.01f * gg);
            acc += fmaxf(gg + e, 0.f);
        }
    }
    for (; p < p1; p += 4) {                 // masked tail, groups of 4
        int idx[4];
#pragma unroll
        for (int j = 0; j < 4; ++j) {
            int q = p + j;
            if (q > p1 - 1) q = p1 - 1;
            idx[j] = srcS[q];
        }
        float g[4];
#pragma unroll
        for (int j = 0; j < 4; ++j)
            g[j] = bfu16(hb[(((unsigned)idx[j]) << 6) + d]);
#pragma unroll
        for (int j = 0; j < 4; ++j) {
            int q = p + j;
            if (q > p1 - 1) q = p1 - 1;
            const uint4* ar = (const uint4*)(attrS + (size_t)q * 8);
            float e = edot(ar[0], ar[1], wq, be);
            float gg = g[j] * cA + cB;
            if (leaky) gg = fmaxf(gg, 0.01f * gg);
            float m = fmaxf(gg + e, 0.f);
            acc += (p + j < p1) ? m : 0.f;
        }
    }
    hv = hv * cA + cB;
    if (leaky) hv = fmaxf(hv, 0.01f * hv);
    zb[(size_t)node * 64 + d] = bf16rn(epsv * hv + acc);
}

// ---------------- MFMA bf16 GEMM: dst = f(src) @ W^T + bias [+resid] ----------------
// Block = 256 thr = 4 waves; tile 64 rows x 64 cols; grid-stride over row tiles.

template <bool BN_IN, bool ABF16, bool STATS, bool RESID, bool BF16OUT, bool F32OUT>
__global__ __launch_bounds__(256) void gemm_mfma(
    const float* __restrict__ srcf, const unsigned short* __restrict__ srcb, int src_ld,
    const unsigned short* __restrict__ Wb,   // bf16 [ncols][64]
    const float* __restrict__ bias,
    float* __restrict__ dst, int dst_ld,
    unsigned short* __restrict__ dstb, int dstb_ld,
    const float* __restrict__ resid,
    const float* __restrict__ statsInSum, const float* __restrict__ statsInSq,
    const float* __restrict__ bnw, const float* __restrict__ bnb,
    float* __restrict__ statsOutSum, float* __restrict__ statsOutSq,
    float* __restrict__ zeroBuf, int zeroN) {
    __shared__ float cA[64], cB[64];
    __shared__ float sS[64], sQ[64];
    int tid = threadIdx.x;
    if (zeroBuf && blockIdx.x == 0 && blockIdx.y == 0 && tid < zeroN) zeroBuf[tid] = 0.f;
    int c0 = blockIdx.y * 64;

    if (BN_IN) {
        if (tid < 64) {
            float m = statsInSum[tid] / FN;
            float v = statsInSq[tid] / FN - m * m;
            float a = rsqrtf(v + BN_EPS) * bnw[tid];
            cA[tid] = a;
            cB[tid] = bnb[tid] - m * a;
        }
        __syncthreads();
    }

    int w = tid >> 6, lane = tid & 63;
    int n16 = lane & 15, quad = lane >> 4;

    // B fragments once per block
    bf16x8 bfr[4][2];
#pragma unroll
    for (int t = 0; t < 4; ++t) {
        int col = c0 + t * 16 + n16;
        const unsigned short* bsrc = Wb + (size_t)col * 64 + quad * 8;
#pragma unroll
        for (int kk = 0; kk < 2; ++kk)
            bfr[t][kk] = *(const bf16x8*)(bsrc + kk * 32);
    }

    float ls[4] = {0.f, 0.f, 0.f, 0.f}, lq[4] = {0.f, 0.f, 0.f, 0.f};
    constexpr int NT = (GN + 63) / 64;  // 1563
    for (int tile = blockIdx.x; tile < NT; tile += gridDim.x) {
        int r0 = tile * 64;
        int arow = r0 + w * 16 + n16;
        int arc = arow < GN ? arow : 0;

        bf16x8 afr[2];
        if (ABF16) {
            const unsigned short* asrc = srcb + (size_t)arc * src_ld + quad * 8;
#pragma unroll
            for (int kk = 0; kk < 2; ++kk) {
                bf16x8 raw = *(const bf16x8*)(asrc + kk * 32);
                if (BN_IN) {
                    int kb = quad * 8 + kk * 32;
                    float av[8];
#pragma unroll
                    for (int j = 0; j < 8; ++j) {
                        float t = bfu16((unsigned short)raw[j]) * cA[kb + j] + cB[kb + j];
                        av[j] = fmaxf(t, 0.01f * t);
                    }
                    uint4 fu;
                    fu.x = packbf2(av[0], av[1]); fu.y = packbf2(av[2], av[3]);
                    fu.z = packbf2(av[4], av[5]); fu.w = packbf2(av[6], av[7]);
                    afr[kk] = __builtin_bit_cast(bf16x8, fu);
                } else {
                    afr[kk] = raw;
                }
            }
        } else {
            const float* asrc = srcf + (size_t)arc * src_ld + quad * 8;
#pragma unroll
            for (int kk = 0; kk < 2; ++kk) {
                const float4* p = (const float4*)(asrc + kk * 32);
                float4 x0 = p[0], x1 = p[1];
                float av[8] = {x0.x, x0.y, x0.z, x0.w, x1.x, x1.y, x1.z, x1.w};
                if (BN_IN) {
                    int kb = quad * 8 + kk * 32;
#pragma unroll
                    for (int j = 0; j < 8; ++j) {
                        float t = av[j] * cA[kb + j] + cB[kb + j];
                        av[j] = fmaxf(t, 0.01f * t);
                    }
                }
                uint4 fu;
                fu.x = packbf2(av[0], av[1]); fu.y = packbf2(av[2], av[3]);
                fu.z = packbf2(av[4], av[5]); fu.w = packbf2(av[6], av[7]);
                afr[kk] = __builtin_bit_cast(bf16x8, fu);
            }
        }

        f32x4 acc[4] = {{0.f, 0.f, 0.f, 0.f}, {0.f, 0.f, 0.f, 0.f},
                        {0.f, 0.f, 0.f, 0.f}, {0.f, 0.f, 0.f, 0.f}};
#pragma unroll
        for (int t = 0; t < 4; ++t) {
            acc[t] = __builtin_amdgcn_mfma_f32_16x16x32_bf16(afr[0], bfr[t][0], acc[t], 0, 0, 0);
            acc[t] = __builtin_amdgcn_mfma_f32_16x16x32_bf16(afr[1], bfr[t][1], acc[t], 0, 0, 0);
        }

        // epilogue: D row = r0 + w*16 + quad*4 + r, col = c0 + t*16 + n16
#pragma unroll
        for (int t = 0; t < 4; ++t) {
            int col = c0 + t * 16 + n16;
            float bv = bias[col];
#pragma unroll
            for (int r = 0; r < 4; ++r) {
                int row = r0 + w * 16 + quad * 4 + r;
                if (row < GN) {
                    float o = acc[t][r] + bv;
                    if (RESID) o += resid[(size_t)row * dst_ld + col];
                    if (F32OUT) dst[(size_t)row * dst_ld + col] = o;
                    if (BF16OUT) dstb[(size_t)row * dstb_ld + col] = bf16rn(o);
                    if (STATS) { ls[t] += o; lq[t] += o * o; }
                }
            }
        }
    }

    if (STATS) {
        if (tid < 64) { sS[tid] = 0.f; sQ[tid] = 0.f; }
        __syncthreads();
#pragma unroll
        for (int t = 0; t < 4; ++t) {
            float s = ls[t], q = lq[t];
            s += __shfl_down(s, 16, 64); s += __shfl_down(s, 32, 64);
            q += __shfl_down(q, 16, 64); q += __shfl_down(q, 32, 64);
            if (lane < 16) {
                atomicAdd(&sS[t * 16 + n16], s);
                atomicAdd(&sQ[t * 16 + n16], q);
            }
        }
        __syncthreads();
        if (tid < 64) {
            atomicAdd(&statsOutSum[c0 + tid], sS[tid]);
            atomicAdd(&statsOutSq[c0 + tid], sQ[tid]);
        }
    }
}

// ---------------- classifier tail (bf16 y1) ----------------

__global__ __launch_bounds__(256) void cls2_kernel(
    const unsigned short* __restrict__ y1b,
    const float* __restrict__ sum, const float* __restrict__ sq,
    const float* __restrict__ bnw, const float* __restrict__ bnb,
    const float* __restrict__ w2, const float* __restrict__ b2,
    float* __restrict__ out) {
    int node = blockIdx.x * 4 + (threadIdx.x >> 6);
    int d = threadIdx.x & 63;
    if (node >= GN) return;
    float partial = 0.f;
#pragma unroll
    for (int hh = 0; hh < 2; ++hh) {
        int c = d + hh * 64;
        float m = sum[c] / FN;
        float var = sq[c] / FN - m * m;
        float a = rsqrtf(var + BN_EPS) * bnw[c];
        float v = bfu16(y1b[(size_t)node * 128 + c]);
        v = v * a + (bnb[c] - m * a);
        v = fmaxf(v, 0.01f * v);
        partial += v * w2[c];
    }
    for (int o = 32; o >= 1; o >>= 1) partial += __shfl_down(partial, o, 64);
    if (d == 0) out[node] = partial + b2[0];
}

// ---------------- launcher ----------------

extern "C" void kernel_launch(void* const* d_in, const int* in_sizes, int n_in,
                              void* d_out, int out_size, void* d_ws, size_t ws_size,
                              hipStream_t stream) {
    (void)in_sizes; (void)n_in; (void)out_size; (void)ws_size;
    const float* x    = (const float*)d_in[0];
    const int*   ei   = (const int*)d_in[1];
    const float* attr = (const float*)d_in[2];
    const float* bnpw = (const float*)d_in[3];
    const float* bnpb = (const float*)d_in[4];
    const float* elw  = (const float*)d_in[5];
    const float* elb  = (const float*)d_in[6];
    const float* l1w  = (const float*)d_in[7];
    const float* l1b  = (const float*)d_in[8];
    const float* bnmw = (const float*)d_in[9];
    const float* bnmb = (const float*)d_in[10];
    const float* l2w  = (const float*)d_in[11];
    const float* l2b  = (const float*)d_in[12];
    const float* epsA = (const float*)d_in[13];
    const float* c1w  = (const float*)d_in[14];
    const float* c1b  = (const float*)d_in[15];
    const float* cbw  = (const float*)d_in[16];
    const float* cbb  = (const float*)d_in[17];
    const float* c2w  = (const float*)d_in[18];
    const float* c2b  = (const float*)d_in[19];
    const int* srcArr = ei;
    const int* dstArr = ei + GE;

    char* base = (char*)d_ws;
    size_t ofs = 0;
    auto alloc = [&](size_t bytes) {
        void* p = base + ofs;
        ofs = (ofs + bytes + 1023) & ~(size_t)1023;
        return p;
    };
    int* off              = (int*)alloc((size_t)(GN + 1) * 4);
    int* cursor           = (int*)alloc((size_t)GN * 4);        // doubles as deg
    int* eids             = (int*)alloc((size_t)GE * 4);
    int* src_sorted       = (int*)alloc((size_t)GE * 4);
    unsigned* attr_sorted = (unsigned*)alloc((size_t)GE * 32);  // bf16 rows, 32B
    unsigned short* wbf   = (unsigned short*)alloc(40960 * 2);
    int* bsum   = (int*)alloc(1024);
    int* bbase  = (int*)alloc(1024);
    float* stP0 = (float*)alloc(512);
    float* stP1 = (float*)alloc(512);
    float* stM  = (float*)alloc(512);
    float* stC  = (float*)alloc(1024);
    float* h = (float*)alloc((size_t)GN * 256);
    unsigned short* zb = (unsigned short*)alloc((size_t)GN * 128);
    unsigned short* tb = (unsigned short*)alloc((size_t)GN * 128);
    unsigned short* xb = (unsigned short*)alloc((size_t)GN * 128);
    unsigned short* hb = (unsigned short*)alloc((size_t)GN * 128);
    unsigned short* y1b = (unsigned short*)attr_sorted;  // reuse (25.6MB <= 51.2MB)

    constexpr int NB = (GN + 1023) / 1024;  // 98
    float* stP[2] = {stP0, stP1};

    // ---- CSR by dst + sorted materialization (scatter perm, gather payload) ----
    hipMemsetAsync(cursor, 0, (size_t)GN * 4, stream);
    hist_kernel<<<2048, 256, 0, stream>>>(dstArr, cursor);
    bsum_kernel<<<NB, 256, 0, stream>>>(cursor, bsum, l1w, l2w, c1w, wbf);
    bscan_kernel<<<1, 64, 0, stream>>>(bsum, bbase, off + GN, NB);
    bscatter_kernel<<<NB, 256, 0, stream>>>(cursor, bbase, off);
    fill_lite_kernel<<<2048, 256, 0, stream>>>(dstArr, cursor, eids, stP0);
    reorder_kernel<<<2048, 256, 0, stream>>>(eids, srcArr, (const float4*)attr,
                                             src_sorted, attr_sorted);

    // ---- layer-0 pre-BN stats on x (+ x -> bf16) ----
    col_stats64<<<512, 256, 0, stream>>>(x, stP0, stP0 + 64, xb);

    const unsigned short* hbsrc = xb;
    dim3 gg(782, 1);
    for (int i = 0; i < 4; ++i) {
        float* sIn = stP[i & 1];
        float* sNext = stP[(i + 1) & 1];
        aggregate_kernel<<<25000, 256, 0, stream>>>(
            hbsrc, sIn, sIn + 64, bnpw + i * 64, bnpb + i * 64, (i > 0) ? 1 : 0,
            off, src_sorted, attr_sorted, elw + i * 1024, elb + i * 64, epsA, i,
            zb, stM);
        // gemm1: tb = zb @ l1w^T + b (bf16 out) ; stats -> stM ; zero next stats
        gemm_mfma<false, true, true, false, true, false><<<gg, 256, 0, stream>>>(
            nullptr, zb, 64, wbf + i * 4096, l1b + i * 64, nullptr, 64, tb, 64,
            nullptr, nullptr, nullptr, nullptr, nullptr, stM, stM + 64,
            (i == 3) ? stC : sNext, (i == 3) ? 256 : 128);
        // gemm2: h = leaky(bn(tb)) @ l2w^T + b [+h] ; stats -> sNext ; bf16 copy
        if (i == 0)
            gemm_mfma<true, true, true, false, true, true><<<gg, 256, 0, stream>>>(
                nullptr, tb, 64, wbf + 16384 + i * 4096, l2b + i * 64, h, 64, hb, 64,
                nullptr, stM, stM + 64, bnmw + i * 64, bnmb + i * 64,
                sNext, sNext + 64, nullptr, 0);
        else if (i < 3)
            gemm_mfma<true, true, true, true, true, true><<<gg, 256, 0, stream>>>(
                nullptr, tb, 64, wbf + 16384 + i * 4096, l2b + i * 64, h, 64, hb, 64,
                h, stM, stM + 64, bnmw + i * 64, bnmb + i * 64,
                sNext, sNext + 64, nullptr, 0);
        else  // last layer: only the bf16 copy is consumed downstream
            gemm_mfma<true, true, false, true, true, false><<<gg, 256, 0, stream>>>(
                nullptr, tb, 64, wbf + 16384 + i * 4096, l2b + i * 64, nullptr, 64,
                hb, 64, h, stM, stM + 64, bnmw + i * 64, bnmb + i * 64,
                nullptr, nullptr, nullptr, 0);
        hbsrc = hb;
    }

    // ---- classifier: y1b = hb @ c1w^T + b (bf16 out), stats -> stC ----
    dim3 gc(391, 2);
    gemm_mfma<false, true, true, false, true, false><<<gc, 256, 0, stream>>>(
        nullptr, hb, 64, wbf + 32768, c1b, nullptr, 128, y1b, 128, nullptr,
        nullptr, nullptr, nullptr, nullptr, stC, stC + 128, nullptr, 0);
    cls2_kernel<<<25000, 256, 0, stream>>>(y1b, stC, stC + 128, cbw, cbb, c2w, c2b,
                                           (float*)d_out);
}